// Round 6
// baseline (151.594 us; speedup 1.0000x reference)
//
#include <hip/hip_runtime.h>
#include <math.h>

#define KE 14.3996f
#define R_MAX 6.0f

// P8: short4 per atom {qx,qy,qz (step 1/512), Z}; exact path (validated R5)
#define PSCALE 512.0f
#define INV_PS2 (1.0f / (512.0f * 512.0f))
// C4: packed 10:10:10 coarse coords, step 0.1, bias 512 (range ~±51.1)
// screen: keep iff int d2 <= 3820  (<=> coarse_dr <= 6.181; quant err <= 0.173)
#define D2_KEEP 3820

// ws layout (floats):
//  [0] ae [1] 1/an [2] pre   [3..6] coeffs   [7..10] exps
//  [16..79] powtab[z]=z^ae
//  [128 .. 128+100K)            C4 table (uint32/atom)
//  [128+131072 .. )             P8 table (short4/atom)
#define WS_POW 16
#define WS_C4  128
#define WS_P8  (128 + 131072)

typedef short s4 __attribute__((ext_vector_type(4)));

__device__ __forceinline__ float softplus_f(float x) {
    return log1pf(expf(x));
}

__global__ void zbl_prep(const float* __restrict__ a_exp,
                         const float* __restrict__ a_num,
                         const float* __restrict__ coefficients,
                         const float* __restrict__ exponents,
                         const float* __restrict__ rep_scale,
                         float* __restrict__ ws,
                         float* __restrict__ out) {
    int t = threadIdx.x;  // 1 block x 64 threads
    float ae = softplus_f(a_exp[0]);
    if (t == 0) {
        ws[0] = ae;
        ws[1] = 1.0f / softplus_f(a_num[0]);
        ws[2] = 0.5f * KE * softplus_f(rep_scale[0]);
        out[0] = 0.0f;   // d_out poisoned 0xAA before every timed call
    }
    if (t < 4) {
        ws[3 + t] = softplus_f(coefficients[t]);
        ws[7 + t] = softplus_f(exponents[t]);
    }
    ws[WS_POW + t] = (t > 0) ? expf(ae * logf((float)t)) : 0.0f;
}

__global__ __launch_bounds__(256) void atom_prep(const float* __restrict__ R,
                                                 const int* __restrict__ Z,
                                                 unsigned int* __restrict__ C4,
                                                 s4* __restrict__ P8,
                                                 int n) {
    int i = blockIdx.x * blockDim.x + threadIdx.x;
    if (i < n) {
        const float x = R[3 * i + 0], y = R[3 * i + 1], z = R[3 * i + 2];
        s4 v;
        v.x = (short)lrintf(x * PSCALE);
        v.y = (short)lrintf(y * PSCALE);
        v.z = (short)lrintf(z * PSCALE);
        v.w = (short)Z[i];
        P8[i] = v;
        int cx = (int)lrintf(x * 10.0f) + 512;
        int cy = (int)lrintf(y * 10.0f) + 512;
        int cz = (int)lrintf(z * 10.0f) + 512;
        cx = min(max(cx, 0), 1023);
        cy = min(max(cy, 0), 1023);
        cz = min(max(cz, 0), 1023);
        C4[i] = (unsigned int)(cx | (cy << 10) | (cz << 20));
    }
}

__device__ __forceinline__ int coarse_keep(unsigned int ca, unsigned int cb) {
    const int dx = (int)(ca & 1023u) - (int)(cb & 1023u);
    const int dy = (int)((ca >> 10) & 1023u) - (int)((cb >> 10) & 1023u);
    const int dz = (int)((ca >> 20) & 1023u) - (int)((cb >> 20) & 1023u);
    const int d2 = dx * dx + dy * dy + dz * dz;   // exact integer screen
    return d2 <= D2_KEEP;
}

__device__ __forceinline__ float edge_term(s4 pa, s4 pb, int i, int j,
                                           const float* __restrict__ R,
                                           const float* __restrict__ spow,
                                           float inv_an,
                                           float c0, float c1, float c2, float c3,
                                           float e0, float e1, float e2, float e3) {
    if (i == j) return 0.0f;   // also catches culled lanes (redirected to 0,0)
    const float dx = (float)(pb.x - pa.x);
    const float dy = (float)(pb.y - pa.y);
    const float dz = (float)(pb.z - pa.z);
    const float dr2 = (dx * dx + dy * dy + dz * dz) * INV_PS2;
    if (dr2 >= R_MAX * R_MAX) return 0.0f;   // cutoff slope 0 at R_MAX: boundary-safe
    float dr;
    if (dr2 < 0.1225f) {
        // rare: 1/dr^2 sensitivity — recompute from exact fp32 R
        const float ax = R[3 * i], ay = R[3 * i + 1], az = R[3 * i + 2];
        const float bx = R[3 * j], by = R[3 * j + 1], bz = R[3 * j + 2];
        const float fx = bx - ax, fy = by - ay, fz = bz - az;
        dr = fmaxf(__fsqrt_rn(fx * fx + fy * fy + fz * fz), 0.02f);
    } else {
        dr = __fsqrt_rn(dr2);
    }
    const float zi = (float)pa.w;
    const float zj = (float)pb.w;
    const float ppa = spow[(int)pa.w] + spow[(int)pb.w];   // Z_i^ae + Z_j^ae
    const float dist = dr * ppa * inv_an;
    const float f = c0 * __expf(-e0 * dist) + c1 * __expf(-e1 * dist)
                  + c2 * __expf(-e2 * dist) + c3 * __expf(-e3 * dist);
    const float cut = 0.5f * (__cosf((float)M_PI / R_MAX * dr) + 1.0f);
    return zi * zj / dr * f * cut;
}

__global__ __launch_bounds__(256) void zbl_edges(
        const unsigned int* __restrict__ C4,
        const s4*    __restrict__ P8,
        const float* __restrict__ R,
        const int*   __restrict__ idx_i,
        const int*   __restrict__ idx_j,
        const float* __restrict__ ws,
        float*       __restrict__ out,
        int nE) {
    __shared__ float spow[64];
    __shared__ float ssc[11];
    if (threadIdx.x < 64) spow[threadIdx.x] = ws[WS_POW + threadIdx.x];
    if (threadIdx.x < 11) ssc[threadIdx.x] = ws[threadIdx.x];
    __syncthreads();

    const float inv_an = ssc[1];
    const float c0 = ssc[3], c1 = ssc[4], c2 = ssc[5], c3 = ssc[6];
    const float e0 = ssc[7], e1 = ssc[8], e2 = ssc[9], e3 = ssc[10];

    float local = 0.0f;
    const int tid = blockIdx.x * blockDim.x + threadIdx.x;
    const int nB = nE >> 3;          // batches of 8 edges

    if (tid < nB) {
        const int e = tid << 3;
        const int4 ii0 = *(const int4*)(idx_i + e);
        const int4 ii1 = *(const int4*)(idx_i + e + 4);
        const int4 jj0 = *(const int4*)(idx_j + e);
        const int4 jj1 = *(const int4*)(idx_j + e + 4);
        // phase 1: 16 independent 4B coarse gathers, issued back-to-back
        const unsigned int ca0 = C4[ii0.x], cb0 = C4[jj0.x];
        const unsigned int ca1 = C4[ii0.y], cb1 = C4[jj0.y];
        const unsigned int ca2 = C4[ii0.z], cb2 = C4[jj0.z];
        const unsigned int ca3 = C4[ii0.w], cb3 = C4[jj0.w];
        const unsigned int ca4 = C4[ii1.x], cb4 = C4[jj1.x];
        const unsigned int ca5 = C4[ii1.y], cb5 = C4[jj1.y];
        const unsigned int ca6 = C4[ii1.z], cb6 = C4[jj1.z];
        const unsigned int ca7 = C4[ii1.w], cb7 = C4[jj1.w];
        // exact integer screen; culled lanes redirect to atom 0 (broadcast line)
        const int k0 = coarse_keep(ca0, cb0), k1 = coarse_keep(ca1, cb1);
        const int k2 = coarse_keep(ca2, cb2), k3 = coarse_keep(ca3, cb3);
        const int k4 = coarse_keep(ca4, cb4), k5 = coarse_keep(ca5, cb5);
        const int k6 = coarse_keep(ca6, cb6), k7 = coarse_keep(ca7, cb7);
        const int gi0 = k0 ? ii0.x : 0, gj0 = k0 ? jj0.x : 0;
        const int gi1 = k1 ? ii0.y : 0, gj1 = k1 ? jj0.y : 0;
        const int gi2 = k2 ? ii0.z : 0, gj2 = k2 ? jj0.z : 0;
        const int gi3 = k3 ? ii0.w : 0, gj3 = k3 ? jj0.w : 0;
        const int gi4 = k4 ? ii1.x : 0, gj4 = k4 ? jj1.x : 0;
        const int gi5 = k5 ? ii1.y : 0, gj5 = k5 ? jj1.y : 0;
        const int gi6 = k6 ? ii1.z : 0, gj6 = k6 ? jj1.z : 0;
        const int gi7 = k7 ? ii1.w : 0, gj7 = k7 ? jj1.w : 0;
        // phase 2: 16 unconditional 8B gathers; ~98% of lanes hit the P8[0]
        // line (intra-wave same-address coalescing + L1 hit) — near-free
        const s4 a0 = P8[gi0], b0 = P8[gj0];
        const s4 a1 = P8[gi1], b1 = P8[gj1];
        const s4 a2 = P8[gi2], b2 = P8[gj2];
        const s4 a3 = P8[gi3], b3 = P8[gj3];
        const s4 a4 = P8[gi4], b4 = P8[gj4];
        const s4 a5 = P8[gi5], b5 = P8[gj5];
        const s4 a6 = P8[gi6], b6 = P8[gj6];
        const s4 a7 = P8[gi7], b7 = P8[gj7];
        local += edge_term(a0, b0, gi0, gj0, R, spow, inv_an, c0,c1,c2,c3, e0,e1,e2,e3);
        local += edge_term(a1, b1, gi1, gj1, R, spow, inv_an, c0,c1,c2,c3, e0,e1,e2,e3);
        local += edge_term(a2, b2, gi2, gj2, R, spow, inv_an, c0,c1,c2,c3, e0,e1,e2,e3);
        local += edge_term(a3, b3, gi3, gj3, R, spow, inv_an, c0,c1,c2,c3, e0,e1,e2,e3);
        local += edge_term(a4, b4, gi4, gj4, R, spow, inv_an, c0,c1,c2,c3, e0,e1,e2,e3);
        local += edge_term(a5, b5, gi5, gj5, R, spow, inv_an, c0,c1,c2,c3, e0,e1,e2,e3);
        local += edge_term(a6, b6, gi6, gj6, R, spow, inv_an, c0,c1,c2,c3, e0,e1,e2,e3);
        local += edge_term(a7, b7, gi7, gj7, R, spow, inv_an, c0,c1,c2,c3, e0,e1,e2,e3);
    }
    // tail (nE % 8 != 0): last block, exact path only
    if (blockIdx.x == gridDim.x - 1) {
        for (int k = (nB << 3) + threadIdx.x; k < nE; k += blockDim.x) {
            const int i = idx_i[k];
            const int j = idx_j[k];
            local += edge_term(P8[i], P8[j], i, j, R, spow, inv_an,
                               c0,c1,c2,c3, e0,e1,e2,e3);
        }
    }

    for (int off = 32; off > 0; off >>= 1)
        local += __shfl_down(local, off);

    __shared__ float wsum[4];
    const int lane = threadIdx.x & 63;
    const int wave = threadIdx.x >> 6;
    if (lane == 0) wsum[wave] = local;
    __syncthreads();
    if (threadIdx.x == 0) {
        const float s = (wsum[0] + wsum[1] + wsum[2] + wsum[3]) * ssc[2];
        atomicAdd(out, s);
    }
}

extern "C" void kernel_launch(void* const* d_in, const int* in_sizes, int n_in,
                              void* d_out, int out_size, void* d_ws, size_t ws_size,
                              hipStream_t stream) {
    const float* R     = (const float*)d_in[0];
    const int*   Z     = (const int*)d_in[1];
    const int*   idx   = (const int*)d_in[2];
    const float* a_exp = (const float*)d_in[3];
    const float* a_num = (const float*)d_in[4];
    const float* coef  = (const float*)d_in[5];
    const float* expo  = (const float*)d_in[6];
    const float* rs    = (const float*)d_in[7];

    float* out = (float*)d_out;
    float* ws  = (float*)d_ws;

    const int nA = in_sizes[0] / 3;
    const int nE = in_sizes[2] / 2;
    const int* idx_i = idx;
    const int* idx_j = idx + nE;

    unsigned int* C4 = (unsigned int*)(ws + WS_C4);
    s4* P8 = (s4*)(ws + WS_P8);

    zbl_prep<<<1, 64, 0, stream>>>(a_exp, a_num, coef, expo, rs, ws, out);
    atom_prep<<<(nA + 255) / 256, 256, 0, stream>>>(R, Z, C4, P8, nA);

    const int block = 256;
    const int nB = nE >> 3;
    const int grid = (nB + block - 1) / block;   // 3125 blocks for 6.4M edges
    zbl_edges<<<grid, block, 0, stream>>>(C4, P8, R, idx_i, idx_j, ws, out, nE);
}